// Round 11
// baseline (6812.139 us; speedup 1.0000x reference)
//
#include <hip/hip_runtime.h>
#include <hip/hip_bf16.h>

#define NN 100000
#define NE 1600000
#define F_IN 512
#define HID 128
#define C_OUT 64
#define L_LAYERS 64
#define SCAN_NB 98  // ceil(NN/1024)

using short8 = __attribute__((ext_vector_type(8))) short;
using f32x4  = __attribute__((ext_vector_type(4))) float;
using u64    = unsigned long long;
typedef __attribute__((ext_vector_type(4))) unsigned short ushort4v;

__device__ __forceinline__ short f2bf(float f) {
    __hip_bfloat16 h = __float2bfloat16(f);
    return __builtin_bit_cast(short, h);
}
__device__ __forceinline__ unsigned short f2bfu(float f) {
    __hip_bfloat16 h = __float2bfloat16(f);
    return __builtin_bit_cast(unsigned short, h);
}
__device__ __forceinline__ float bflo(unsigned u) { return __uint_as_float(u << 16); }
__device__ __forceinline__ float bfhi(unsigned u) { return __uint_as_float(u & 0xffff0000u); }
__device__ __forceinline__ float bf2f(unsigned short u) { return __uint_as_float((unsigned)u << 16); }
__device__ __forceinline__ int2 ld_nt_i2(const int2* p) {
    u64 v = __builtin_nontemporal_load((const u64*)p);
    return make_int2((int)(unsigned)v, (int)(unsigned)(v >> 32));
}

// ---------------- preprocessing ----------------

__global__ void count_deg(const int* __restrict__ dst, int* __restrict__ cnt) {
    int e = blockIdx.x * blockDim.x + threadIdx.x;
    if (e < NE) atomicAdd(&cnt[dst[e]], 1);
}

__global__ void compute_dinv(const int* __restrict__ cnt, float* __restrict__ dinv) {
    int n = blockIdx.x * blockDim.x + threadIdx.x;
    if (n < NN) dinv[n] = rsqrtf((float)cnt[n] + 1.0f);
}

__global__ __launch_bounds__(256) void scan1(const int* __restrict__ cnt,
                                             int* __restrict__ row_ptr,
                                             int* __restrict__ partial) {
    __shared__ int sdata[256];
    int tid = threadIdx.x;
    int base = blockIdx.x * 1024;
    int v[4];
    int idx0 = base + tid * 4;
#pragma unroll
    for (int i = 0; i < 4; ++i) {
        int idx = idx0 + i;
        v[i] = (idx < NN) ? cnt[idx] : 0;
    }
    int s = v[0] + v[1] + v[2] + v[3];
    sdata[tid] = s;
    __syncthreads();
    int x = s;
    for (int off = 1; off < 256; off <<= 1) {
        int y = (tid >= off) ? sdata[tid - off] : 0;
        __syncthreads();
        x += y;
        sdata[tid] = x;
        __syncthreads();
    }
    int run = x - s;
#pragma unroll
    for (int i = 0; i < 4; ++i) {
        int idx = idx0 + i;
        if (idx < NN) row_ptr[idx] = run;
        run += v[i];
    }
    if (tid == 255) partial[blockIdx.x] = x;
}

__global__ __launch_bounds__(128) void scan2(int* __restrict__ partial) {
    __shared__ int sdata[128];
    int tid = threadIdx.x;
    int v = (tid < SCAN_NB) ? partial[tid] : 0;
    sdata[tid] = v;
    __syncthreads();
    int x = v;
    for (int off = 1; off < 128; off <<= 1) {
        int y = (tid >= off) ? sdata[tid - off] : 0;
        __syncthreads();
        x += y;
        sdata[tid] = x;
        __syncthreads();
    }
    if (tid < SCAN_NB) partial[tid] = x - v;
}

// add block offsets; pad row_ptr[NN..NN+64] = NE for OOB wave preloads
__global__ void scan3(int* __restrict__ row_ptr, const int* __restrict__ partial) {
    int idx = blockIdx.x * blockDim.x + threadIdx.x;
    if (idx < NN) row_ptr[idx] += partial[idx >> 10];
    else if (idx <= NN + 64) row_ptr[idx] = NE;
}

// pack (src, weight-bits) per edge for broadcast in the gather
__global__ void scatter_csr(const int* __restrict__ src, const int* __restrict__ dst,
                            const float* __restrict__ dinv, int* __restrict__ fill,
                            int2* __restrict__ edges) {
    int e = blockIdx.x * blockDim.x + threadIdx.x;
    if (e >= NE) return;
    int s = src[e], d = dst[e];
    int pos = atomicAdd(&fill[d], 1);
    edges[pos] = make_int2(s, __float_as_int(dinv[s] * dinv[d]));
}

__global__ __launch_bounds__(256) void prep_wt(const float* __restrict__ Wc,
                                               const float* __restrict__ Win,
                                               __hip_bfloat16* __restrict__ WT,
                                               __hip_bfloat16* __restrict__ WinT) {
    int b = blockIdx.x, tid = threadIdx.x;
    if (b < 64) {
        const float* src = Wc + (size_t)b * HID * HID;
        __hip_bfloat16* dstp = WT + (size_t)b * HID * HID;
        for (int it = 0; it < 64; ++it) {
            int idx = it * 256 + tid;           // n*128 + k
            int n = idx >> 7, k = idx & 127;
            dstp[idx] = __float2bfloat16(src[k * HID + n]);
        }
    } else {
        int j = b - 64;
        for (int it = 0; it < 16; ++it) {
            int gid = j * 4096 + it * 256 + tid;  // n*512 + k
            int n = gid >> 9, k = gid & 511;
            WinT[gid] = __float2bfloat16(Win[k * HID + n]);
        }
    }
}

// ---------------- x0 = relu(X @ W_in + b), bf16 MFMA, BM=64, double-buffered ----------------
__global__ __launch_bounds__(256) void gemm_x0_mfma(const float* __restrict__ X,
                                                    const __hip_bfloat16* __restrict__ WinT,
                                                    const float* __restrict__ bias,
                                                    __hip_bfloat16* __restrict__ X0b) {
    // per buf: Xs 64x32 (2048 shorts) + Ws 128x32 (4096 shorts) = 6144; x2 bufs = 24KB
    __shared__ short SMEM[12288];
    int tid = threadIdx.x;
    int w = tid >> 6, l = tid & 63, g = l >> 4, r = l & 15;
    int row0 = blockIdx.x * 64;
    f32x4 acc[8] = {};

    float4 sx0, sx1;   // X regs: 1 chunk/thread
    uint4 sw[2];       // W regs: 2 chunks/thread
    auto load_regs = [&](int kt) {
        int k0 = kt * 32;
        int rr = tid >> 2, slot = tid & 3;
        int grow = row0 + rr;
        sx0 = make_float4(0.f, 0.f, 0.f, 0.f); sx1 = sx0;
        if (grow < NN) {
            sx0 = *(const float4*)&X[(size_t)grow * F_IN + k0 + slot * 8];
            sx1 = *(const float4*)&X[(size_t)grow * F_IN + k0 + slot * 8 + 4];
        }
#pragma unroll
        for (int i = 0; i < 2; ++i) {
            int id = i * 256 + tid;
            int rw = id >> 2, slw = id & 3;
            sw[i] = *(const uint4*)&WinT[(size_t)rw * F_IN + k0 + slw * 8];
        }
    };

    load_regs(0);
    for (int kt = 0; kt < 16; ++kt) {
        short* Xs = SMEM + (kt & 1) * 6144;
        short* Wsh = Xs + 2048;
        {
            int rr = tid >> 2, slot = tid & 3;
            short8 p;
            p[0] = f2bf(sx0.x); p[1] = f2bf(sx0.y); p[2] = f2bf(sx0.z); p[3] = f2bf(sx0.w);
            p[4] = f2bf(sx1.x); p[5] = f2bf(sx1.y); p[6] = f2bf(sx1.z); p[7] = f2bf(sx1.w);
            *(short8*)&Xs[rr * 32 + (slot ^ ((rr >> 1) & 3)) * 8] = p;
#pragma unroll
            for (int i = 0; i < 2; ++i) {
                int id = i * 256 + tid;
                int rw = id >> 2, slw = id & 3;
                *(uint4*)&Wsh[rw * 32 + (slw ^ ((rw >> 1) & 3)) * 8] = sw[i];
            }
        }
        __syncthreads();
        if (kt < 15) load_regs(kt + 1);
        short8 a, bb[8];
        {
            int row = w * 16 + r;
            a = *(short8*)&Xs[row * 32 + (g ^ ((row >> 1) & 3)) * 8];
        }
#pragma unroll
        for (int n = 0; n < 8; ++n) {
            int row = n * 16 + r;
            bb[n] = *(short8*)&Wsh[row * 32 + (g ^ ((row >> 1) & 3)) * 8];
        }
#pragma unroll
        for (int n = 0; n < 8; ++n)
            acc[n] = __builtin_amdgcn_mfma_f32_16x16x32_bf16(a, bb[n], acc[n], 0, 0, 0);
    }
    __syncthreads();
    // stage bias+relu into SMEM (64x128 shorts, swizzled 16B chunks), then coop store
#pragma unroll
    for (int n = 0; n < 8; ++n) {
        int col = n * 16 + r;
        float bv = bias[col];
#pragma unroll
        for (int q = 0; q < 4; ++q) {
            int row = w * 16 + g * 4 + q;
            float v = fmaxf(acc[n][q] + bv, 0.f);
            SMEM[row * 128 + ((col >> 3) ^ (row & 15)) * 8 + (col & 7)] = f2bf(v);
        }
    }
    __syncthreads();
    // 64 rows x 16 chunks = 1024 uint4 over 256 threads x 4 iters
#pragma unroll
    for (int i = 0; i < 4; ++i) {
        int id = i * 256 + tid;
        int rr = id >> 4, c8 = id & 15;
        int grow = row0 + rr;
        if (grow < NN)
            *(uint4*)&X0b[(size_t)grow * HID + c8 * 8] =
                *(uint4*)&SMEM[rr * 128 + ((c8 ^ (rr & 15)) * 8)];
    }
}

// ---------------- fused layer v3c: 64-node tile, paired-node gather, 12-deep, NT streams ----------------
// 512 threads = 8 waves; each wave gathers 8 nodes (4 pairs); LDS: Ts 16KB + Ws 32KB
__global__ __launch_bounds__(512, 6) void layer_fused(const unsigned* __restrict__ H2,
                                                      const unsigned* __restrict__ X02,
                                                      const float* __restrict__ dinv,
                                                      const int* __restrict__ row_ptr,
                                                      const int2* __restrict__ edges,
                                                      const __hip_bfloat16* __restrict__ WTl,
                                                      float beta,
                                                      __hip_bfloat16* __restrict__ Hout,
                                                      float* __restrict__ Zf) {
    __shared__ short Ts[64 * 128];
    __shared__ short Ws[128 * 128];
    int tid = threadIdx.x;
    int w = tid >> 6, l = tid & 63, g = l >> 4, r = l & 15;
    int row0 = blockIdx.x * 64;

    // load W tile (swizzled 16-slot XOR): 2048 uint4 over 512 threads
#pragma unroll
    for (int i = 0; i < 4; ++i) {
        int id = i * 512 + tid;
        int rr = id >> 4, slot = id & 15;
        uint4 wv = *(const uint4*)&WTl[(size_t)id * 8];
        *(uint4*)&Ws[rr * 128 + (slot ^ (rr & 15)) * 8] = wv;
    }

    // gather: wave w -> nodes row0 + w*8 .. +7, processed as 4 concurrent pairs
    unsigned* TsU = (unsigned*)Ts;
    int nb0 = row0 + w * 8;
    int ep[9];
#pragma unroll
    for (int k = 0; k < 9; ++k) ep[k] = __builtin_amdgcn_readfirstlane(row_ptr[nb0 + k]);

#pragma unroll
    for (int j = 0; j < 4; ++j) {
        int rrA = w * 8 + 2 * j, rrB = rrA + 1;
        int nA = row0 + rrA, nB = nA + 1;
        bool vA = nA < NN, vB = nB < NN;
        unsigned hsA = vA ? H2[((unsigned)nA << 6) + l] : 0u;
        unsigned hsB = vB ? H2[((unsigned)nB << 6) + l] : 0u;
        unsigned xvA = vA ? __builtin_nontemporal_load(&X02[((unsigned)nA << 6) + l]) : 0u;
        unsigned xvB = vB ? __builtin_nontemporal_load(&X02[((unsigned)nB << 6) + l]) : 0u;
        float dvA = vA ? dinv[nA] : 0.f, dvB = vB ? dinv[nB] : 0.f;
        float a0A = dvA * dvA * bflo(hsA), a1A = dvA * dvA * bfhi(hsA);
        float a0B = dvB * dvB * bflo(hsB), a1B = dvB * dvB * bfhi(hsB);
        int eA = ep[2 * j], e1A = ep[2 * j + 1];
        int eB = e1A, e1B = ep[2 * j + 2];
        while (eA < e1A || eB < e1B) {
            int cA = e1A - eA; cA = cA > 12 ? 12 : (cA < 0 ? 0 : cA);
            int cB = e1B - eB; cB = cB > 12 ? 12 : (cB < 0 ? 0 : cB);
            int sA[12], sB[12];
            float wA[12], wB[12];
#pragma unroll
            for (int u = 0; u < 12; ++u) {
                int2 t = ld_nt_i2(&edges[eA + u]);
                sA[u] = (u < cA) ? t.x : 0;
                wA[u] = (u < cA) ? __int_as_float(t.y) : 0.f;
            }
#pragma unroll
            for (int u = 0; u < 12; ++u) {
                int2 t = ld_nt_i2(&edges[eB + u]);
                sB[u] = (u < cB) ? t.x : 0;
                wB[u] = (u < cB) ? __int_as_float(t.y) : 0.f;
            }
            unsigned hvA[12], hvB[12];
#pragma unroll
            for (int u = 0; u < 12; ++u) hvA[u] = H2[((unsigned)sA[u] << 6) + l];
#pragma unroll
            for (int u = 0; u < 12; ++u) hvB[u] = H2[((unsigned)sB[u] << 6) + l];
#pragma unroll
            for (int u = 0; u < 12; ++u) {
                a0A = fmaf(wA[u], bflo(hvA[u]), a0A);
                a1A = fmaf(wA[u], bfhi(hvA[u]), a1A);
                a0B = fmaf(wB[u], bflo(hvB[u]), a0B);
                a1B = fmaf(wB[u], bfhi(hvB[u]), a1B);
            }
            eA += cA; eB += cB;
        }
        a0A = 0.9f * a0A + 0.1f * bflo(xvA);  a1A = 0.9f * a1A + 0.1f * bfhi(xvA);
        a0B = 0.9f * a0B + 0.1f * bflo(xvB);  a1B = 0.9f * a1B + 0.1f * bfhi(xvB);
        unsigned pkA = (unsigned)f2bfu(a0A) | ((unsigned)f2bfu(a1A) << 16);
        unsigned pkB = (unsigned)f2bfu(a0B) | ((unsigned)f2bfu(a1B) << 16);
        TsU[rrA * 64 + ((l >> 2) ^ (rrA & 15)) * 4 + (l & 3)] = pkA;
        TsU[rrB * 64 + ((l >> 2) ^ (rrB & 15)) * 4 + (l & 3)] = pkB;
    }
    __syncthreads();

    // MFMA phase: wave w -> node-block nb = w&3 (16 nodes), channel-group cg = w>>2 (64 ch)
    int nb = w & 3, cg = w >> 2;
    f32x4 acc[4] = {};
#pragma unroll
    for (int ks = 0; ks < 4; ++ks) {
        int rrT = nb * 16 + r;
        short8 bT = *(short8*)&Ts[rrT * 128 + ((ks * 4 + g) ^ (rrT & 15)) * 8];
        short8 aW[4];
#pragma unroll
        for (int c = 0; c < 4; ++c) {
            int rrW = (cg * 4 + c) * 16 + r;
            aW[c] = *(short8*)&Ws[rrW * 128 + ((ks * 4 + g) ^ (rrW & 15)) * 8];
        }
#pragma unroll
        for (int c = 0; c < 4; ++c)
            acc[c] = __builtin_amdgcn_mfma_f32_16x16x32_bf16(aW[c], bT, acc[c], 0, 0, 0);
    }

    // epilogue: lane holds channels (cg*4+c)*16 + g*4 .. +3 of node nb*16+r (NT stores)
    float omb = 1.0f - beta;
    int node = nb * 16 + r;
    int grow = row0 + node;
    if (grow < NN) {
#pragma unroll
        for (int c = 0; c < 4; ++c) {
            int c0 = (cg * 4 + c) * 16 + g * 4;
            int slotE = c0 >> 3, posE = c0 & 7;
            ushort4v tv = *(ushort4v*)&Ts[node * 128 + (slotE ^ (node & 15)) * 8 + posE];
            float o[4];
#pragma unroll
            for (int q = 0; q < 4; ++q)
                o[q] = fmaxf(omb * bf2f(tv[q]) + beta * acc[c][q], 0.f);
            if (Zf) {
                f32x4 ov = {o[0], o[1], o[2], o[3]};
                __builtin_nontemporal_store(ov, (f32x4*)&Zf[(size_t)grow * HID + c0]);
            } else {
                ushort4v hv;
#pragma unroll
                for (int q = 0; q < 4; ++q) hv[q] = f2bfu(o[q]);
                __builtin_nontemporal_store(hv, (ushort4v*)&Hout[(size_t)grow * HID + c0]);
            }
        }
    }
}

// ---------------- final: LDS-tiled logits + log_softmax, 64 nodes/block ----------------
__global__ __launch_bounds__(256) void final_kernel(const float* __restrict__ Z,
                                                    const float* __restrict__ Wout,
                                                    const float* __restrict__ bout,
                                                    float* __restrict__ lo) {
    __shared__ float Wl[128 * 64];    // [k][c], 32KB
    __shared__ float Zl[64][128];     // 32KB
    int tid = threadIdx.x;
    int w = tid >> 6, c = tid & 63;
    int n0 = blockIdx.x * 64;
#pragma unroll
    for (int i = 0; i < 8; ++i) {
        int id = i * 256 + tid;
        *(float4*)&Wl[id * 4] = *(const float4*)&Wout[(size_t)id * 4];
    }
#pragma unroll
    for (int i = 0; i < 8; ++i) {
        int id = i * 256 + tid;
        int rr = id >> 5, c4 = id & 31;
        int n = n0 + rr;
        float4 v = make_float4(0.f, 0.f, 0.f, 0.f);
        if (n < NN) v = *(const float4*)&Z[(size_t)n * HID + c4 * 4];
        *(float4*)&Zl[rr][c4 * 4] = v;
    }
    __syncthreads();
    float bv = bout[c];
#pragma unroll
    for (int i = 0; i < 4; ++i) {
        int nodeb = i * 16 + w * 4;
        float l0 = 0.f, l1 = 0.f, l2 = 0.f, l3 = 0.f;
#pragma unroll 8
        for (int k = 0; k < 128; ++k) {
            float wv = Wl[k * 64 + c];
            l0 = fmaf(Zl[nodeb + 0][k], wv, l0);
            l1 = fmaf(Zl[nodeb + 1][k], wv, l1);
            l2 = fmaf(Zl[nodeb + 2][k], wv, l2);
            l3 = fmaf(Zl[nodeb + 3][k], wv, l3);
        }
        float lg[4] = {l0 + bv, l1 + bv, l2 + bv, l3 + bv};
#pragma unroll
        for (int j = 0; j < 4; ++j) {
            float logit = lg[j];
            float m = logit;
#pragma unroll
            for (int off = 32; off; off >>= 1) m = fmaxf(m, __shfl_xor(m, off));
            float ex = __expf(logit - m);
            float ssum = ex;
#pragma unroll
            for (int off = 32; off; off >>= 1) ssum += __shfl_xor(ssum, off);
            int n = n0 + nodeb + j;
            if (n < NN) lo[(size_t)n * C_OUT + c] = logit - m - logf(ssum);
        }
    }
}

extern "C" void kernel_launch(void* const* d_in, const int* in_sizes, int n_in,
                              void* d_out, int out_size, void* d_ws, size_t ws_size,
                              hipStream_t stream) {
    const float* x = (const float*)d_in[0];
    const int* ei = (const int*)d_in[1];
    const int* src = ei;
    const int* dst = ei + NE;
    const float* W_in = (const float*)d_in[2];
    const float* b_in = (const float*)d_in[3];
    const float* W_convs = (const float*)d_in[4];
    const float* W_out = (const float*)d_in[5];
    const float* b_out = (const float*)d_in[6];
    float* out = (float*)d_out;

    char* ws = (char*)d_ws;
    float* dinv = (float*)ws;              ws += (size_t)NN * 4;
    int* row_ptr = (int*)ws;               ws += (size_t)(NN + 72) * 4;
    int* fill = (int*)ws;                  ws += (size_t)NN * 4;
    int* partial = (int*)ws;               ws += (size_t)128 * 4;
    int2* edges = (int2*)ws;               ws += (size_t)(NE + 32) * 8;
    __hip_bfloat16* WT = (__hip_bfloat16*)ws;   ws += (size_t)L_LAYERS * HID * HID * 2;
    __hip_bfloat16* WinT = (__hip_bfloat16*)ws; ws += (size_t)F_IN * HID * 2;
    __hip_bfloat16* x0b = (__hip_bfloat16*)ws;  ws += (size_t)NN * HID * 2;
    __hip_bfloat16* HbA = (__hip_bfloat16*)ws;  ws += (size_t)NN * HID * 2;
    __hip_bfloat16* HbB = (__hip_bfloat16*)ws;  ws += (size_t)NN * HID * 2;

    hipMemsetAsync(fill, 0, (size_t)NN * 4, stream);
    count_deg<<<(NE + 255) / 256, 256, 0, stream>>>(dst, fill);
    compute_dinv<<<(NN + 255) / 256, 256, 0, stream>>>(fill, dinv);
    scan1<<<SCAN_NB, 256, 0, stream>>>(fill, row_ptr, partial);
    scan2<<<1, 128, 0, stream>>>(partial);
    scan3<<<(NN + 255) / 256, 256, 0, stream>>>(row_ptr, partial);
    hipMemcpyAsync(fill, row_ptr, (size_t)NN * 4, hipMemcpyDeviceToDevice, stream);
    scatter_csr<<<(NE + 255) / 256, 256, 0, stream>>>(src, dst, dinv, fill, edges);
    prep_wt<<<80, 256, 0, stream>>>(W_convs, W_in, WT, WinT);

    int gemm_blocks = (NN + 63) / 64;
    gemm_x0_mfma<<<gemm_blocks, 256, 0, stream>>>(x, WinT, b_in, x0b);

    int layer_blocks = (NN + 63) / 64;
    float* zf = out;  // last layer writes fp32 z directly into d_out
    for (int l = 0; l < L_LAYERS; ++l) {
        const __hip_bfloat16* h_in = (l == 0) ? x0b : ((l & 1) ? HbA : HbB);
        __hip_bfloat16* h_out = (l & 1) ? HbB : HbA;
        float beta = logf(0.5f / (float)(l + 1) + 1.0f);
        bool last = (l == L_LAYERS - 1);
        layer_fused<<<layer_blocks, 512, 0, stream>>>(
            (const unsigned*)h_in, (const unsigned*)x0b, dinv, row_ptr, edges,
            WT + (size_t)l * HID * HID, beta,
            h_out, last ? zf : (float*)nullptr);
    }

    final_kernel<<<(NN + 63) / 64, 256, 0, stream>>>(zf, W_out, b_out, out + (size_t)NN * HID);
}

// Round 12
// 6352.262 us; speedup vs baseline: 1.0724x; 1.0724x over previous
//
#include <hip/hip_runtime.h>
#include <hip/hip_bf16.h>

#define NN 100000
#define NE 1600000
#define F_IN 512
#define HID 128
#define C_OUT 64
#define L_LAYERS 64
#define SCAN_NB 98  // ceil(NN/1024)

using short8 = __attribute__((ext_vector_type(8))) short;
using f32x4  = __attribute__((ext_vector_type(4))) float;
typedef __attribute__((ext_vector_type(4))) unsigned short ushort4v;

__device__ __forceinline__ short f2bf(float f) {
    __hip_bfloat16 h = __float2bfloat16(f);
    return __builtin_bit_cast(short, h);
}
__device__ __forceinline__ unsigned short f2bfu(float f) {
    __hip_bfloat16 h = __float2bfloat16(f);
    return __builtin_bit_cast(unsigned short, h);
}
__device__ __forceinline__ float bflo(unsigned u) { return __uint_as_float(u << 16); }
__device__ __forceinline__ float bfhi(unsigned u) { return __uint_as_float(u & 0xffff0000u); }
__device__ __forceinline__ float bf2f(unsigned short u) { return __uint_as_float((unsigned)u << 16); }

// ---------------- preprocessing ----------------

__global__ void count_deg(const int* __restrict__ dst, int* __restrict__ cnt) {
    int e = blockIdx.x * blockDim.x + threadIdx.x;
    if (e < NE) atomicAdd(&cnt[dst[e]], 1);
}

__global__ void compute_dinv(const int* __restrict__ cnt, float* __restrict__ dinv) {
    int n = blockIdx.x * blockDim.x + threadIdx.x;
    if (n < NN) dinv[n] = rsqrtf((float)cnt[n] + 1.0f);
}

__global__ __launch_bounds__(256) void scan1(const int* __restrict__ cnt,
                                             int* __restrict__ row_ptr,
                                             int* __restrict__ partial) {
    __shared__ int sdata[256];
    int tid = threadIdx.x;
    int base = blockIdx.x * 1024;
    int v[4];
    int idx0 = base + tid * 4;
#pragma unroll
    for (int i = 0; i < 4; ++i) {
        int idx = idx0 + i;
        v[i] = (idx < NN) ? cnt[idx] : 0;
    }
    int s = v[0] + v[1] + v[2] + v[3];
    sdata[tid] = s;
    __syncthreads();
    int x = s;
    for (int off = 1; off < 256; off <<= 1) {
        int y = (tid >= off) ? sdata[tid - off] : 0;
        __syncthreads();
        x += y;
        sdata[tid] = x;
        __syncthreads();
    }
    int run = x - s;
#pragma unroll
    for (int i = 0; i < 4; ++i) {
        int idx = idx0 + i;
        if (idx < NN) row_ptr[idx] = run;
        run += v[i];
    }
    if (tid == 255) partial[blockIdx.x] = x;
}

__global__ __launch_bounds__(128) void scan2(int* __restrict__ partial) {
    __shared__ int sdata[128];
    int tid = threadIdx.x;
    int v = (tid < SCAN_NB) ? partial[tid] : 0;
    sdata[tid] = v;
    __syncthreads();
    int x = v;
    for (int off = 1; off < 128; off <<= 1) {
        int y = (tid >= off) ? sdata[tid - off] : 0;
        __syncthreads();
        x += y;
        sdata[tid] = x;
        __syncthreads();
    }
    if (tid < SCAN_NB) partial[tid] = x - v;
}

// add block offsets; pad row_ptr[NN..NN+64] = NE for OOB wave preloads
__global__ void scan3(int* __restrict__ row_ptr, const int* __restrict__ partial) {
    int idx = blockIdx.x * blockDim.x + threadIdx.x;
    if (idx < NN) row_ptr[idx] += partial[idx >> 10];
    else if (idx <= NN + 64) row_ptr[idx] = NE;
}

// pack (src, weight-bits) per edge
__global__ void scatter_csr(const int* __restrict__ src, const int* __restrict__ dst,
                            const float* __restrict__ dinv, int* __restrict__ fill,
                            int2* __restrict__ edges) {
    int e = blockIdx.x * blockDim.x + threadIdx.x;
    if (e >= NE) return;
    int s = src[e], d = dst[e];
    int pos = atomicAdd(&fill[d], 1);
    edges[pos] = make_int2(s, __float_as_int(dinv[s] * dinv[d]));
}

__global__ __launch_bounds__(256) void prep_wt(const float* __restrict__ Wc,
                                               const float* __restrict__ Win,
                                               __hip_bfloat16* __restrict__ WT,
                                               __hip_bfloat16* __restrict__ WinT) {
    int b = blockIdx.x, tid = threadIdx.x;
    if (b < 64) {
        const float* src = Wc + (size_t)b * HID * HID;
        __hip_bfloat16* dstp = WT + (size_t)b * HID * HID;
        for (int it = 0; it < 64; ++it) {
            int idx = it * 256 + tid;           // n*128 + k
            int n = idx >> 7, k = idx & 127;
            dstp[idx] = __float2bfloat16(src[k * HID + n]);
        }
    } else {
        int j = b - 64;
        for (int it = 0; it < 16; ++it) {
            int gid = j * 4096 + it * 256 + tid;  // n*512 + k
            int n = gid >> 9, k = gid & 511;
            WinT[gid] = __float2bfloat16(Win[k * HID + n]);
        }
    }
}

// ---------------- x0 = relu(X @ W_in + b), bf16 MFMA, BM=64, double-buffered ----------------
__global__ __launch_bounds__(256) void gemm_x0_mfma(const float* __restrict__ X,
                                                    const __hip_bfloat16* __restrict__ WinT,
                                                    const float* __restrict__ bias,
                                                    __hip_bfloat16* __restrict__ X0b) {
    // per buf: Xs 64x32 (2048 shorts) + Ws 128x32 (4096 shorts) = 6144; x2 bufs = 24KB
    __shared__ short SMEM[12288];
    int tid = threadIdx.x;
    int w = tid >> 6, l = tid & 63, g = l >> 4, r = l & 15;
    int row0 = blockIdx.x * 64;
    f32x4 acc[8] = {};

    float4 sx0, sx1;   // X regs: 1 chunk/thread
    uint4 sw[2];       // W regs: 2 chunks/thread
    auto load_regs = [&](int kt) {
        int k0 = kt * 32;
        int rr = tid >> 2, slot = tid & 3;
        int grow = row0 + rr;
        sx0 = make_float4(0.f, 0.f, 0.f, 0.f); sx1 = sx0;
        if (grow < NN) {
            sx0 = *(const float4*)&X[(size_t)grow * F_IN + k0 + slot * 8];
            sx1 = *(const float4*)&X[(size_t)grow * F_IN + k0 + slot * 8 + 4];
        }
#pragma unroll
        for (int i = 0; i < 2; ++i) {
            int id = i * 256 + tid;
            int rw = id >> 2, slw = id & 3;
            sw[i] = *(const uint4*)&WinT[(size_t)rw * F_IN + k0 + slw * 8];
        }
    };

    load_regs(0);
    for (int kt = 0; kt < 16; ++kt) {
        short* Xs = SMEM + (kt & 1) * 6144;
        short* Wsh = Xs + 2048;
        {
            int rr = tid >> 2, slot = tid & 3;
            short8 p;
            p[0] = f2bf(sx0.x); p[1] = f2bf(sx0.y); p[2] = f2bf(sx0.z); p[3] = f2bf(sx0.w);
            p[4] = f2bf(sx1.x); p[5] = f2bf(sx1.y); p[6] = f2bf(sx1.z); p[7] = f2bf(sx1.w);
            *(short8*)&Xs[rr * 32 + (slot ^ ((rr >> 1) & 3)) * 8] = p;
#pragma unroll
            for (int i = 0; i < 2; ++i) {
                int id = i * 256 + tid;
                int rw = id >> 2, slw = id & 3;
                *(uint4*)&Wsh[rw * 32 + (slw ^ ((rw >> 1) & 3)) * 8] = sw[i];
            }
        }
        __syncthreads();
        if (kt < 15) load_regs(kt + 1);
        short8 a, bb[8];
        {
            int row = w * 16 + r;
            a = *(short8*)&Xs[row * 32 + (g ^ ((row >> 1) & 3)) * 8];
        }
#pragma unroll
        for (int n = 0; n < 8; ++n) {
            int row = n * 16 + r;
            bb[n] = *(short8*)&Wsh[row * 32 + (g ^ ((row >> 1) & 3)) * 8];
        }
#pragma unroll
        for (int n = 0; n < 8; ++n)
            acc[n] = __builtin_amdgcn_mfma_f32_16x16x32_bf16(a, bb[n], acc[n], 0, 0, 0);
    }
    __syncthreads();
    // stage bias+relu into SMEM (64x128 shorts, swizzled 16B chunks), then coop store
#pragma unroll
    for (int n = 0; n < 8; ++n) {
        int col = n * 16 + r;
        float bv = bias[col];
#pragma unroll
        for (int q = 0; q < 4; ++q) {
            int row = w * 16 + g * 4 + q;
            float v = fmaxf(acc[n][q] + bv, 0.f);
            SMEM[row * 128 + ((col >> 3) ^ (row & 15)) * 8 + (col & 7)] = f2bf(v);
        }
    }
    __syncthreads();
    // 64 rows x 16 chunks = 1024 uint4 over 256 threads x 4 iters
#pragma unroll
    for (int i = 0; i < 4; ++i) {
        int id = i * 256 + tid;
        int rr = id >> 4, c8 = id & 15;
        int grow = row0 + rr;
        if (grow < NN)
            *(uint4*)&X0b[(size_t)grow * HID + c8 * 8] =
                *(uint4*)&SMEM[rr * 128 + ((c8 ^ (rr & 15)) * 8)];
    }
}

// ---------------- fused layer v3 (R7 best-known): 64-node tile, paired gather, 8-deep ----------------
// 512 threads = 8 waves; each wave gathers 8 nodes (4 pairs); LDS: Ts 16KB + Ws 32KB
__global__ __launch_bounds__(512, 6) void layer_fused(const unsigned* __restrict__ H2,
                                                      const unsigned* __restrict__ X02,
                                                      const float* __restrict__ dinv,
                                                      const int* __restrict__ row_ptr,
                                                      const int2* __restrict__ edges,
                                                      const __hip_bfloat16* __restrict__ WTl,
                                                      float beta,
                                                      __hip_bfloat16* __restrict__ Hout,
                                                      float* __restrict__ Zf) {
    __shared__ short Ts[64 * 128];
    __shared__ short Ws[128 * 128];
    int tid = threadIdx.x;
    int w = tid >> 6, l = tid & 63, g = l >> 4, r = l & 15;
    int row0 = blockIdx.x * 64;

    // load W tile (swizzled 16-slot XOR): 2048 uint4 over 512 threads
#pragma unroll
    for (int i = 0; i < 4; ++i) {
        int id = i * 512 + tid;
        int rr = id >> 4, slot = id & 15;
        uint4 wv = *(const uint4*)&WTl[(size_t)id * 8];
        *(uint4*)&Ws[rr * 128 + (slot ^ (rr & 15)) * 8] = wv;
    }

    // gather: wave w -> nodes row0 + w*8 .. +7, processed as 4 concurrent pairs
    unsigned* TsU = (unsigned*)Ts;
    int nb0 = row0 + w * 8;
    int ep[9];
#pragma unroll
    for (int k = 0; k < 9; ++k) ep[k] = __builtin_amdgcn_readfirstlane(row_ptr[nb0 + k]);

#pragma unroll
    for (int j = 0; j < 4; ++j) {
        int rrA = w * 8 + 2 * j, rrB = rrA + 1;
        int nA = row0 + rrA, nB = nA + 1;
        bool vA = nA < NN, vB = nB < NN;
        unsigned hsA = vA ? H2[((unsigned)nA << 6) + l] : 0u;
        unsigned hsB = vB ? H2[((unsigned)nB << 6) + l] : 0u;
        unsigned xvA = vA ? X02[((unsigned)nA << 6) + l] : 0u;
        unsigned xvB = vB ? X02[((unsigned)nB << 6) + l] : 0u;
        float dvA = vA ? dinv[nA] : 0.f, dvB = vB ? dinv[nB] : 0.f;
        float a0A = dvA * dvA * bflo(hsA), a1A = dvA * dvA * bfhi(hsA);
        float a0B = dvB * dvB * bflo(hsB), a1B = dvB * dvB * bfhi(hsB);
        int eA = ep[2 * j], e1A = ep[2 * j + 1];
        int eB = e1A, e1B = ep[2 * j + 2];
        while (eA < e1A || eB < e1B) {
            int cA = e1A - eA; cA = cA > 8 ? 8 : (cA < 0 ? 0 : cA);
            int cB = e1B - eB; cB = cB > 8 ? 8 : (cB < 0 ? 0 : cB);
            int sA[8], sB[8];
            float wA[8], wB[8];
#pragma unroll
            for (int u = 0; u < 8; ++u) {
                int2 t = edges[eA + u];
                sA[u] = (u < cA) ? t.x : 0;
                wA[u] = (u < cA) ? __int_as_float(t.y) : 0.f;
            }
#pragma unroll
            for (int u = 0; u < 8; ++u) {
                int2 t = edges[eB + u];
                sB[u] = (u < cB) ? t.x : 0;
                wB[u] = (u < cB) ? __int_as_float(t.y) : 0.f;
            }
            unsigned hvA[8], hvB[8];
#pragma unroll
            for (int u = 0; u < 8; ++u) hvA[u] = H2[((unsigned)sA[u] << 6) + l];
#pragma unroll
            for (int u = 0; u < 8; ++u) hvB[u] = H2[((unsigned)sB[u] << 6) + l];
#pragma unroll
            for (int u = 0; u < 8; ++u) {
                a0A = fmaf(wA[u], bflo(hvA[u]), a0A);
                a1A = fmaf(wA[u], bfhi(hvA[u]), a1A);
                a0B = fmaf(wB[u], bflo(hvB[u]), a0B);
                a1B = fmaf(wB[u], bfhi(hvB[u]), a1B);
            }
            eA += cA; eB += cB;
        }
        a0A = 0.9f * a0A + 0.1f * bflo(xvA);  a1A = 0.9f * a1A + 0.1f * bfhi(xvA);
        a0B = 0.9f * a0B + 0.1f * bflo(xvB);  a1B = 0.9f * a1B + 0.1f * bfhi(xvB);
        unsigned pkA = (unsigned)f2bfu(a0A) | ((unsigned)f2bfu(a1A) << 16);
        unsigned pkB = (unsigned)f2bfu(a0B) | ((unsigned)f2bfu(a1B) << 16);
        TsU[rrA * 64 + ((l >> 2) ^ (rrA & 15)) * 4 + (l & 3)] = pkA;
        TsU[rrB * 64 + ((l >> 2) ^ (rrB & 15)) * 4 + (l & 3)] = pkB;
    }
    __syncthreads();

    // MFMA phase: wave w -> node-block nb = w&3 (16 nodes), channel-group cg = w>>2 (64 ch)
    int nb = w & 3, cg = w >> 2;
    f32x4 acc[4] = {};
#pragma unroll
    for (int ks = 0; ks < 4; ++ks) {
        int rrT = nb * 16 + r;
        short8 bT = *(short8*)&Ts[rrT * 128 + ((ks * 4 + g) ^ (rrT & 15)) * 8];
        short8 aW[4];
#pragma unroll
        for (int c = 0; c < 4; ++c) {
            int rrW = (cg * 4 + c) * 16 + r;
            aW[c] = *(short8*)&Ws[rrW * 128 + ((ks * 4 + g) ^ (rrW & 15)) * 8];
        }
#pragma unroll
        for (int c = 0; c < 4; ++c)
            acc[c] = __builtin_amdgcn_mfma_f32_16x16x32_bf16(aW[c], bT, acc[c], 0, 0, 0);
    }

    // epilogue: lane holds channels (cg*4+c)*16 + g*4 .. +3 of node nb*16+r
    float omb = 1.0f - beta;
    int node = nb * 16 + r;
    int grow = row0 + node;
    if (grow < NN) {
#pragma unroll
        for (int c = 0; c < 4; ++c) {
            int c0 = (cg * 4 + c) * 16 + g * 4;
            int slotE = c0 >> 3, posE = c0 & 7;
            ushort4v tv = *(ushort4v*)&Ts[node * 128 + (slotE ^ (node & 15)) * 8 + posE];
            float o[4];
#pragma unroll
            for (int q = 0; q < 4; ++q)
                o[q] = fmaxf(omb * bf2f(tv[q]) + beta * acc[c][q], 0.f);
            if (Zf) {
                *(float4*)&Zf[(size_t)grow * HID + c0] = make_float4(o[0], o[1], o[2], o[3]);
            } else {
                ushort4v hv;
#pragma unroll
                for (int q = 0; q < 4; ++q) hv[q] = f2bfu(o[q]);
                *(ushort4v*)&Hout[(size_t)grow * HID + c0] = hv;
            }
        }
    }
}

// ---------------- final: LDS-tiled logits + log_softmax, 64 nodes/block ----------------
__global__ __launch_bounds__(256) void final_kernel(const float* __restrict__ Z,
                                                    const float* __restrict__ Wout,
                                                    const float* __restrict__ bout,
                                                    float* __restrict__ lo) {
    __shared__ float Wl[128 * 64];    // [k][c], 32KB
    __shared__ float Zl[64][128];     // 32KB
    int tid = threadIdx.x;
    int w = tid >> 6, c = tid & 63;
    int n0 = blockIdx.x * 64;
#pragma unroll
    for (int i = 0; i < 8; ++i) {
        int id = i * 256 + tid;
        *(float4*)&Wl[id * 4] = *(const float4*)&Wout[(size_t)id * 4];
    }
#pragma unroll
    for (int i = 0; i < 8; ++i) {
        int id = i * 256 + tid;
        int rr = id >> 5, c4 = id & 31;
        int n = n0 + rr;
        float4 v = make_float4(0.f, 0.f, 0.f, 0.f);
        if (n < NN) v = *(const float4*)&Z[(size_t)n * HID + c4 * 4];
        *(float4*)&Zl[rr][c4 * 4] = v;
    }
    __syncthreads();
    float bv = bout[c];
#pragma unroll
    for (int i = 0; i < 4; ++i) {
        int nodeb = i * 16 + w * 4;
        float l0 = 0.f, l1 = 0.f, l2 = 0.f, l3 = 0.f;
#pragma unroll 8
        for (int k = 0; k < 128; ++k) {
            float wv = Wl[k * 64 + c];
            l0 = fmaf(Zl[nodeb + 0][k], wv, l0);
            l1 = fmaf(Zl[nodeb + 1][k], wv, l1);
            l2 = fmaf(Zl[nodeb + 2][k], wv, l2);
            l3 = fmaf(Zl[nodeb + 3][k], wv, l3);
        }
        float lg[4] = {l0 + bv, l1 + bv, l2 + bv, l3 + bv};
#pragma unroll
        for (int j = 0; j < 4; ++j) {
            float logit = lg[j];
            float m = logit;
#pragma unroll
            for (int off = 32; off; off >>= 1) m = fmaxf(m, __shfl_xor(m, off));
            float ex = __expf(logit - m);
            float ssum = ex;
#pragma unroll
            for (int off = 32; off; off >>= 1) ssum += __shfl_xor(ssum, off);
            int n = n0 + nodeb + j;
            if (n < NN) lo[(size_t)n * C_OUT + c] = logit - m - logf(ssum);
        }
    }
}

extern "C" void kernel_launch(void* const* d_in, const int* in_sizes, int n_in,
                              void* d_out, int out_size, void* d_ws, size_t ws_size,
                              hipStream_t stream) {
    const float* x = (const float*)d_in[0];
    const int* ei = (const int*)d_in[1];
    const int* src = ei;
    const int* dst = ei + NE;
    const float* W_in = (const float*)d_in[2];
    const float* b_in = (const float*)d_in[3];
    const float* W_convs = (const float*)d_in[4];
    const float* W_out = (const float*)d_in[5];
    const float* b_out = (const float*)d_in[6];
    float* out = (float*)d_out;

    char* ws = (char*)d_ws;
    float* dinv = (float*)ws;              ws += (size_t)NN * 4;
    int* row_ptr = (int*)ws;               ws += (size_t)(NN + 72) * 4;
    int* fill = (int*)ws;                  ws += (size_t)NN * 4;
    int* partial = (int*)ws;               ws += (size_t)128 * 4;
    int2* edges = (int2*)ws;               ws += (size_t)(NE + 32) * 8;
    __hip_bfloat16* WT = (__hip_bfloat16*)ws;   ws += (size_t)L_LAYERS * HID * HID * 2;
    __hip_bfloat16* WinT = (__hip_bfloat16*)ws; ws += (size_t)F_IN * HID * 2;
    __hip_bfloat16* x0b = (__hip_bfloat16*)ws;  ws += (size_t)NN * HID * 2;
    __hip_bfloat16* HbA = (__hip_bfloat16*)ws;  ws += (size_t)NN * HID * 2;
    __hip_bfloat16* HbB = (__hip_bfloat16*)ws;  ws += (size_t)NN * HID * 2;

    hipMemsetAsync(fill, 0, (size_t)NN * 4, stream);
    count_deg<<<(NE + 255) / 256, 256, 0, stream>>>(dst, fill);
    compute_dinv<<<(NN + 255) / 256, 256, 0, stream>>>(fill, dinv);
    scan1<<<SCAN_NB, 256, 0, stream>>>(fill, row_ptr, partial);
    scan2<<<1, 128, 0, stream>>>(partial);
    scan3<<<(NN + 255) / 256, 256, 0, stream>>>(row_ptr, partial);
    hipMemcpyAsync(fill, row_ptr, (size_t)NN * 4, hipMemcpyDeviceToDevice, stream);
    scatter_csr<<<(NE + 255) / 256, 256, 0, stream>>>(src, dst, dinv, fill, edges);
    prep_wt<<<80, 256, 0, stream>>>(W_convs, W_in, WT, WinT);

    int gemm_blocks = (NN + 63) / 64;
    gemm_x0_mfma<<<gemm_blocks, 256, 0, stream>>>(x, WinT, b_in, x0b);

    int layer_blocks = (NN + 63) / 64;
    float* zf = out;  // last layer writes fp32 z directly into d_out
    for (int l = 0; l < L_LAYERS; ++l) {
        const __hip_bfloat16* h_in = (l == 0) ? x0b : ((l & 1) ? HbA : HbB);
        __hip_bfloat16* h_out = (l & 1) ? HbB : HbA;
        float beta = logf(0.5f / (float)(l + 1) + 1.0f);
        bool last = (l == L_LAYERS - 1);
        layer_fused<<<layer_blocks, 512, 0, stream>>>(
            (const unsigned*)h_in, (const unsigned*)x0b, dinv, row_ptr, edges,
            WT + (size_t)l * HID * HID, beta,
            h_out, last ? zf : (float*)nullptr);
    }

    final_kernel<<<(NN + 63) / 64, 256, 0, stream>>>(zf, W_out, b_out, out + (size_t)NN * HID);
}